// Round 1
// baseline (4210.160 us; speedup 1.0000x reference)
//
#include <hip/hip_runtime.h>

// EIRNN: B=256,T=512,I=128,H=512,O=64; alpha=0.2, softplus beta=8, thresh=20.
// Design: 144 persistent blocks = 16 row-groups (16 batch rows each) x
// (8 matvec shards of 64 h-columns + 1 readout block). W_hh/W_xh/W_out shards
// live in REGISTERS as constant f16 MFMA B-fragments (64 VGPRs) for all 512
// steps. Per step: h (f16) exchanged via double-buffered global buffer;
// lock-step sync per row-group with one agent-scope counter per (r,t).
// h integrator state kept fp32 in registers (only MFMA operands rounded).

#define BB 256
#define TT 512
#define II 128
#define HH 512
#define OO 64
#define RG 16   // batch rows per row-group
#define JC 64   // h-columns per matvec shard

typedef _Float16 f16;
typedef f16 f16x8 __attribute__((ext_vector_type(8)));
typedef float f32x4 __attribute__((ext_vector_type(4)));

#define RDY_STRIDE 520  // per-r counter row (t = 0..512)

__global__ __launch_bounds__(256, 1)
void eirnn_persist(const float* __restrict__ x,
                   const float* __restrict__ Wxh,
                   const float* __restrict__ Whh,
                   const float* __restrict__ bh,
                   const float* __restrict__ Wout,
                   const float* __restrict__ bout,
                   float* __restrict__ yout,
                   f16* __restrict__ hbuf,          // 2 * B * H f16 (double buffer)
                   unsigned int* __restrict__ ready) // 16 * RDY_STRIDE u32, zeroed
{
    const int tid  = threadIdx.x;
    const int bid  = blockIdx.x;
    const int wave = tid >> 6;
    const int lane = tid & 63;
    const int quad = lane >> 4;
    const int l16  = lane & 15;

    // 144 blocks: xcd-round-robin friendly mapping; r-group = 16 co-synced blocks
    const int xcd  = bid & 7;
    const int slot = bid >> 3;              // 0..17
    const int r    = xcd * 2 + (slot & 1);  // 0..15
    const int c    = slot >> 1;             // 0..8
    const bool isY = (c == 8);
    const int rowbase = r * RG;
    const int jbase   = c * JC;             // valid when !isY

    __shared__ __align__(16) f16 hg[RG][HH + 8];   // gathered h_t (f16), padded
    __shared__ __align__(16) f16 xsh[RG][II + 8];  // staged x_t tile (f16)

    unsigned int* rdy = ready + r * RDY_STRIDE;

    // ---- one-time: weight shards -> constant register B-fragments ----
    // B-frag (gemm_bt): lane holds BT[n = lane&15][k = quad*8 + j], j=0..7
    const int myrow = wave * 16 + l16;  // shard-local j row (or o row for Y)
    f16x8 bf[16];   // W_hh shard (K=512 -> 16 k-steps)  [or W_out for Y block]
    f16x8 xbf[4];   // W_xh shard (K=128 -> 4 k-steps)
    float bias;

    if (!isY) {
        const float* wp = Whh + (size_t)(jbase + myrow) * HH + quad * 8;
        #pragma unroll
        for (int ks = 0; ks < 16; ++ks) {
            float4 u = *(const float4*)(wp + ks * 32);
            float4 v = *(const float4*)(wp + ks * 32 + 4);
            f16x8 t;
            t[0] = (f16)u.x; t[1] = (f16)u.y; t[2] = (f16)u.z; t[3] = (f16)u.w;
            t[4] = (f16)v.x; t[5] = (f16)v.y; t[6] = (f16)v.z; t[7] = (f16)v.w;
            bf[ks] = t;
        }
        const float* wq = Wxh + (size_t)(jbase + myrow) * II + quad * 8;
        #pragma unroll
        for (int ks = 0; ks < 4; ++ks) {
            float4 u = *(const float4*)(wq + ks * 32);
            float4 v = *(const float4*)(wq + ks * 32 + 4);
            f16x8 t;
            t[0] = (f16)u.x; t[1] = (f16)u.y; t[2] = (f16)u.z; t[3] = (f16)u.w;
            t[4] = (f16)v.x; t[5] = (f16)v.y; t[6] = (f16)v.z; t[7] = (f16)v.w;
            xbf[ks] = t;
        }
        bias = bh[jbase + myrow];
    } else {
        const float* wp = Wout + (size_t)myrow * HH + quad * 8;
        #pragma unroll
        for (int ks = 0; ks < 16; ++ks) {
            float4 u = *(const float4*)(wp + ks * 32);
            float4 v = *(const float4*)(wp + ks * 32 + 4);
            f16x8 t;
            t[0] = (f16)u.x; t[1] = (f16)u.y; t[2] = (f16)u.z; t[3] = (f16)u.w;
            t[4] = (f16)v.x; t[5] = (f16)v.y; t[6] = (f16)v.z; t[7] = (f16)v.w;
            bf[ks] = t;
        }
        bias = bout[myrow];
    }

    // zero gathered-h tile (t=0 uses h_0 = 0)
    for (int p = tid; p < RG * (HH + 8) / 2; p += 256)
        ((unsigned int*)hg)[p] = 0u;

    // fp32 integrator state: this lane owns h[m = quad*4+reg][jbase+myrow]
    float hreg[4] = {0.f, 0.f, 0.f, 0.f};

    // software-prefetch x tile for t=0 (matvec blocks): 2 float4 per thread
    float4 xpf0, xpf1;
    if (!isY) {
        int p0 = tid, p1 = tid + 256;
        int row0 = p0 >> 5, c40 = p0 & 31;
        int row1 = p1 >> 5, c41 = p1 & 31;
        xpf0 = ((const float4*)(x + ((size_t)(rowbase + row0) * TT + 0) * II))[c40];
        xpf1 = ((const float4*)(x + ((size_t)(rowbase + row1) * TT + 0) * II))[c41];
    }

    __syncthreads();

    const int tmax = isY ? TT : (TT - 1);
    for (int t = 0; t <= tmax; ++t) {
        // ---- A: wait for h_t, gather into LDS ----
        if (t >= 1) {
            if (tid == 0) {
                while (__hip_atomic_load(&rdy[t - 1], __ATOMIC_RELAXED,
                                         __HIP_MEMORY_SCOPE_AGENT) < 9u)
                    __builtin_amdgcn_s_sleep(1);
            }
            __syncthreads();
            __builtin_amdgcn_fence(__ATOMIC_ACQUIRE, "agent");
            const f16* src = hbuf + (size_t)(t & 1) * BB * HH + (size_t)rowbase * HH;
            #pragma unroll
            for (int p = tid; p < RG * (HH / 8); p += 256) {
                int row = p >> 6, c8 = p & 63;
                uint4 v = ((const uint4*)(src + (size_t)row * HH))[c8];
                *(uint4*)&hg[row][c8 * 8] = v;
            }
        }

        // ---- B: stage x_t tile from prefetch regs ----
        if (!isY) {
            int p0 = tid, p1 = tid + 256;
            int row0 = p0 >> 5, c40 = p0 & 31;
            int row1 = p1 >> 5, c41 = p1 & 31;
            f16* d0 = &xsh[row0][c40 * 4];
            d0[0] = (f16)xpf0.x; d0[1] = (f16)xpf0.y; d0[2] = (f16)xpf0.z; d0[3] = (f16)xpf0.w;
            f16* d1 = &xsh[row1][c41 * 4];
            d1[0] = (f16)xpf1.x; d1[1] = (f16)xpf1.y; d1[2] = (f16)xpf1.z; d1[3] = (f16)xpf1.w;
        }
        __syncthreads();

        // ---- D: prefetch x for t+1 (overlaps MFMA + next sync) ----
        if (!isY && (t + 1) <= tmax) {
            int p0 = tid, p1 = tid + 256;
            int row0 = p0 >> 5, c40 = p0 & 31;
            int row1 = p1 >> 5, c41 = p1 & 31;
            xpf0 = ((const float4*)(x + ((size_t)(rowbase + row0) * TT + (t + 1)) * II))[c40];
            xpf1 = ((const float4*)(x + ((size_t)(rowbase + row1) * TT + (t + 1)) * II))[c41];
        }

        if (isY) {
            // consumption of h_t certified after the gather barrier above
            if (tid == 0 && t < TT)
                __hip_atomic_fetch_add(&rdy[t], 1u, __ATOMIC_RELEASE,
                                       __HIP_MEMORY_SCOPE_AGENT);
            if (t >= 1) {
                // y_{t-1} = h_t . W_out^T + b_out
                f32x4 acc0 = {0.f, 0.f, 0.f, 0.f}, acc1 = {0.f, 0.f, 0.f, 0.f};
                #pragma unroll
                for (int ks = 0; ks < 16; ks += 2) {
                    f16x8 a0 = *(const f16x8*)&hg[l16][ks * 32 + quad * 8];
                    f16x8 a1 = *(const f16x8*)&hg[l16][(ks + 1) * 32 + quad * 8];
                    acc0 = __builtin_amdgcn_mfma_f32_16x16x32_f16(a0, bf[ks], acc0, 0, 0, 0);
                    acc1 = __builtin_amdgcn_mfma_f32_16x16x32_f16(a1, bf[ks + 1], acc1, 0, 0, 0);
                }
                #pragma unroll
                for (int reg = 0; reg < 4; ++reg) {
                    int m = quad * 4 + reg;
                    float yv = acc0[reg] + acc1[reg] + bias;
                    yout[((size_t)(rowbase + m) * TT + (t - 1)) * OO + myrow] = yv;
                }
            }
        } else {
            // pre = h_t . W_hh^T + x_t . W_xh^T + b_h   (C/D: row=quad*4+reg -> m,
            // col=lane&15 -> j; A-frag: lane holds A[m=lane&15][k=quad*8+j])
            f32x4 acc0 = {0.f, 0.f, 0.f, 0.f}, acc1 = {0.f, 0.f, 0.f, 0.f};
            #pragma unroll
            for (int ks = 0; ks < 16; ks += 2) {
                f16x8 a0 = *(const f16x8*)&hg[l16][ks * 32 + quad * 8];
                f16x8 a1 = *(const f16x8*)&hg[l16][(ks + 1) * 32 + quad * 8];
                acc0 = __builtin_amdgcn_mfma_f32_16x16x32_f16(a0, bf[ks], acc0, 0, 0, 0);
                acc1 = __builtin_amdgcn_mfma_f32_16x16x32_f16(a1, bf[ks + 1], acc1, 0, 0, 0);
            }
            #pragma unroll
            for (int ks = 0; ks < 4; ks += 2) {
                f16x8 a0 = *(const f16x8*)&xsh[l16][ks * 32 + quad * 8];
                f16x8 a1 = *(const f16x8*)&xsh[l16][(ks + 1) * 32 + quad * 8];
                acc0 = __builtin_amdgcn_mfma_f32_16x16x32_f16(a0, xbf[ks], acc0, 0, 0, 0);
                acc1 = __builtin_amdgcn_mfma_f32_16x16x32_f16(a1, xbf[ks + 1], acc1, 0, 0, 0);
            }
            // phi + leaky update; write h_{t+1} slice (f16) to the other buffer
            f16* dst = hbuf + (size_t)((t + 1) & 1) * BB * HH;
            #pragma unroll
            for (int reg = 0; reg < 4; ++reg) {
                int m = quad * 4 + reg;
                float pre = acc0[reg] + acc1[reg] + bias;
                float z = 8.f * pre;
                float ph = (z > 20.f) ? pre : (__logf(1.f + __expf(z)) * 0.125f);
                float hn = 0.8f * hreg[reg] + 0.2f * ph;
                hreg[reg] = hn;
                dst[(size_t)(rowbase + m) * HH + jbase + myrow] = (f16)hn;
            }
            __syncthreads();  // drains all waves' global h stores (vmcnt before barrier)
            if (tid == 0)
                __hip_atomic_fetch_add(&rdy[t], 1u, __ATOMIC_RELEASE,
                                       __HIP_MEMORY_SCOPE_AGENT);
        }
    }
}

extern "C" void kernel_launch(void* const* d_in, const int* in_sizes, int n_in,
                              void* d_out, int out_size, void* d_ws, size_t ws_size,
                              hipStream_t stream)
{
    const float* x    = (const float*)d_in[0];
    const float* Wxh  = (const float*)d_in[1];
    const float* Whh  = (const float*)d_in[2];
    const float* bh   = (const float*)d_in[3];
    const float* Wout = (const float*)d_in[4];
    const float* bout = (const float*)d_in[5];
    float* yout = (float*)d_out;

    f16* hbuf = (f16*)d_ws;
    const size_t hbuf_bytes = (size_t)2 * BB * HH * sizeof(f16);      // 512 KB
    unsigned int* ready = (unsigned int*)((char*)d_ws + hbuf_bytes);
    const size_t rdy_bytes = (size_t)16 * RDY_STRIDE * sizeof(unsigned int);

    if (ws_size < hbuf_bytes + rdy_bytes) return;  // would be a harness bug

    hipMemsetAsync(ready, 0, rdy_bytes, stream);

    // 144 blocks <= 256 CUs, ~27 KB LDS, <=256 VGPR -> all co-resident.
    eirnn_persist<<<dim3(144), dim3(256), 0, stream>>>(
        x, Wxh, Whh, bh, Wout, bout, yout, hbuf, ready);
}

// Round 2
// 1495.602 us; speedup vs baseline: 2.8150x; 2.8150x over previous
//
#include <hip/hip_runtime.h>

// EIRNN: B=256,T=512,I=128,H=512,O=64; alpha=0.2, softplus beta=8, thresh=20.
// R1: persistent-block recurrence, 16 row-groups x 8 shard-blocks (128 blocks,
// all co-resident on 256 CUs). Weights live in registers as f16 MFMA B-frags.
// h exchange: RELAXED agent-scope atomics only (per-access sc1 -> write-through
// to Infinity Cache) -- NO acquire/release fences (those emit buffer_inv /
// buffer_wbl2 cache-wide ops; R0 measured 8.2us/step from exactly that).
// Release = sc1 h-stores + s_waitcnt(0) + per-wave monotonic flag store.
// Acquire = control-dependent sc1 loads after flag observation.
// Readout y = K-split (64 per block) partials via atomicAdd into zeroed d_out.

#define BB 256
#define TT 512
#define II 128
#define HH 512
#define OO 64
#define RG 16   // batch rows per row-group
#define JC 64   // h-columns per shard block
#define NG 16   // row-groups
#define NC 8    // shard blocks per group

typedef _Float16 f16;
typedef f16 f16x8 __attribute__((ext_vector_type(8)));
typedef float f32x4 __attribute__((ext_vector_type(4)));

__global__ __launch_bounds__(256, 1)
void eirnn_persist(const float* __restrict__ x,
                   const float* __restrict__ Wxh,
                   const float* __restrict__ Whh,
                   const float* __restrict__ bh,
                   const float* __restrict__ Wout,
                   const float* __restrict__ bout,
                   float* __restrict__ yout,
                   f16* __restrict__ hbuf,           // 2*B*H f16 double buffer
                   unsigned int* __restrict__ flg)   // NG*NC*4 u32 monotonic flags
{
    const int tid  = threadIdx.x;
    const int bid  = blockIdx.x;
    const int wave = tid >> 6;
    const int lane = tid & 63;
    const int quad = lane >> 4;
    const int l16  = lane & 15;
    const int r    = bid >> 3;        // row-group
    const int c    = bid & 7;         // shard
    const int rowbase = r * RG;
    const int jbase   = c * JC;
    const int myrow   = wave * 16 + l16;

    __shared__ __align__(16) f16 hg[RG][HH + 8];   // gathered h_t
    __shared__ __align__(16) f16 xsh[RG][II + 8];  // staged x_t

    // ---- one-time: weight shards -> constant register B-fragments ----
    // B-frag: lane holds BT[n=lane&15][k=quad*8+j], j=0..7 (verified R0)
    f16x8 bf[16];   // W_hh shard, K=512 -> 16 k-steps
    f16x8 xbf[4];   // W_xh shard, K=128 -> 4 k-steps
    f16x8 bfo[2];   // W_out, this block's K-range [c*64, c*64+64)
    {
        const float* wp = Whh + (size_t)(jbase + myrow) * HH + quad * 8;
        #pragma unroll
        for (int ks = 0; ks < 16; ++ks) {
            float4 u = *(const float4*)(wp + ks * 32);
            float4 v = *(const float4*)(wp + ks * 32 + 4);
            f16x8 tv;
            tv[0]=(f16)u.x; tv[1]=(f16)u.y; tv[2]=(f16)u.z; tv[3]=(f16)u.w;
            tv[4]=(f16)v.x; tv[5]=(f16)v.y; tv[6]=(f16)v.z; tv[7]=(f16)v.w;
            bf[ks] = tv;
        }
        const float* wq = Wxh + (size_t)(jbase + myrow) * II + quad * 8;
        #pragma unroll
        for (int ks = 0; ks < 4; ++ks) {
            float4 u = *(const float4*)(wq + ks * 32);
            float4 v = *(const float4*)(wq + ks * 32 + 4);
            f16x8 tv;
            tv[0]=(f16)u.x; tv[1]=(f16)u.y; tv[2]=(f16)u.z; tv[3]=(f16)u.w;
            tv[4]=(f16)v.x; tv[5]=(f16)v.y; tv[6]=(f16)v.z; tv[7]=(f16)v.w;
            xbf[ks] = tv;
        }
        const float* wo = Wout + (size_t)myrow * HH + c * 64 + quad * 8;
        #pragma unroll
        for (int ks = 0; ks < 2; ++ks) {
            float4 u = *(const float4*)(wo + ks * 32);
            float4 v = *(const float4*)(wo + ks * 32 + 4);
            f16x8 tv;
            tv[0]=(f16)u.x; tv[1]=(f16)u.y; tv[2]=(f16)u.z; tv[3]=(f16)u.w;
            tv[4]=(f16)v.x; tv[5]=(f16)v.y; tv[6]=(f16)v.z; tv[7]=(f16)v.w;
            bfo[ks] = tv;
        }
    }
    const float biash = bh[jbase + myrow];
    const float biaso = (c == 0) ? bout[myrow] : 0.0f;

    // zero gathered-h tile (t=0 uses h_0 = 0)
    for (int p = tid; p < RG * (HH + 8) / 2; p += 256)
        ((unsigned int*)hg)[p] = 0u;

    // fp32 integrator state: lane owns h[m=quad*4+reg][jbase+myrow]
    float hreg[4] = {0.f, 0.f, 0.f, 0.f};

    // gather geometry: thread reads u64s at col8=tid&127 (fixed) -> exactly one
    // producer (shard, wave): shard=col8>>4, producer wave pw=(tid&15)>>2.
    const int col8  = tid & 127;
    const int shard = col8 >> 4;
    const int pw    = (tid & 15) >> 2;
    const int row0  = tid >> 7;                      // rows row0+2i, i=0..7
    const unsigned int* fpoll = flg + ((r * NC + shard) * 4 + pw);
    unsigned int* fmine = flg + ((r * NC + c) * 4 + wave);

    // x prefetch for t=0: 2 float4/thread cover 16 rows x 128 cols
    float4 xpf0, xpf1;
    {
        int p0 = tid, p1 = tid + 256;
        xpf0 = ((const float4*)(x + ((size_t)(rowbase + (p0 >> 5)) * TT + 0) * II))[p0 & 31];
        xpf1 = ((const float4*)(x + ((size_t)(rowbase + (p1 >> 5)) * TT + 0) * II))[p1 & 31];
    }

    __syncthreads();

    for (int t = 0; t <= TT; ++t) {
        // ---- stage x_t from prefetch regs (xsh reads of t-1 ended before B2) ----
        if (t < TT) {
            int p0 = tid, p1 = tid + 256;
            f16* d0 = &xsh[p0 >> 5][(p0 & 31) * 4];
            d0[0]=(f16)xpf0.x; d0[1]=(f16)xpf0.y; d0[2]=(f16)xpf0.z; d0[3]=(f16)xpf0.w;
            f16* d1 = &xsh[p1 >> 5][(p1 & 31) * 4];
            d1[0]=(f16)xpf1.x; d1[1]=(f16)xpf1.y; d1[2]=(f16)xpf1.z; d1[3]=(f16)xpf1.w;
        }
        // ---- issue x_{t+1} prefetch BEFORE the poll: spin's vmcnt(0) absorbs it ----
        if (t + 1 < TT) {
            int p0 = tid, p1 = tid + 256;
            xpf0 = ((const float4*)(x + ((size_t)(rowbase + (p0 >> 5)) * TT + (t + 1)) * II))[p0 & 31];
            xpf1 = ((const float4*)(x + ((size_t)(rowbase + (p1 >> 5)) * TT + (t + 1)) * II))[p1 & 31];
        }
        // ---- wait for my producer wave, gather my h_t strip (sc1, IF-coherent) ----
        if (t >= 1) {
            while (__hip_atomic_load(fpoll, __ATOMIC_RELAXED, __HIP_MEMORY_SCOPE_AGENT)
                   < (unsigned)t) {}
            const unsigned long long* src = (const unsigned long long*)hbuf
                + (size_t)(t & 1) * (BB * HH / 4) + (size_t)rowbase * (HH / 4) + col8;
            unsigned long long v[8];
            #pragma unroll
            for (int i = 0; i < 8; ++i)
                v[i] = __hip_atomic_load(src + (size_t)(row0 + 2 * i) * (HH / 4),
                                         __ATOMIC_RELAXED, __HIP_MEMORY_SCOPE_AGENT);
            #pragma unroll
            for (int i = 0; i < 8; ++i)
                *(unsigned long long*)&hg[row0 + 2 * i][col8 * 4] = v[i];
        }
        __syncthreads();   // B1: hg + xsh ready

        if (t < TT) {
            // pre = h_t.W_hh^T + x_t.W_xh^T + b_h
            f32x4 acc0 = {0.f,0.f,0.f,0.f}, acc1 = {0.f,0.f,0.f,0.f};
            #pragma unroll
            for (int ks = 0; ks < 16; ks += 2) {
                f16x8 a0 = *(const f16x8*)&hg[l16][ks * 32 + quad * 8];
                f16x8 a1 = *(const f16x8*)&hg[l16][(ks + 1) * 32 + quad * 8];
                acc0 = __builtin_amdgcn_mfma_f32_16x16x32_f16(a0, bf[ks], acc0, 0, 0, 0);
                acc1 = __builtin_amdgcn_mfma_f32_16x16x32_f16(a1, bf[ks + 1], acc1, 0, 0, 0);
            }
            #pragma unroll
            for (int ks = 0; ks < 4; ks += 2) {
                f16x8 a0 = *(const f16x8*)&xsh[l16][ks * 32 + quad * 8];
                f16x8 a1 = *(const f16x8*)&xsh[l16][(ks + 1) * 32 + quad * 8];
                acc0 = __builtin_amdgcn_mfma_f32_16x16x32_f16(a0, xbf[ks], acc0, 0, 0, 0);
                acc1 = __builtin_amdgcn_mfma_f32_16x16x32_f16(a1, xbf[ks + 1], acc1, 0, 0, 0);
            }
            // phi + leaky update; pack lane-pairs -> u32 sc1 stores (write-through)
            unsigned int* dstw = (unsigned int*)hbuf + (size_t)((t + 1) & 1) * (BB * HH / 2);
            unsigned int hb[4];
            #pragma unroll
            for (int reg = 0; reg < 4; ++reg) {
                float pre = acc0[reg] + acc1[reg] + biash;
                float z = 8.f * pre;
                float ph = (z > 20.f) ? pre : (__logf(1.f + __expf(z)) * 0.125f);
                float hn = 0.8f * hreg[reg] + 0.2f * ph;
                hreg[reg] = hn;
                hb[reg] = (unsigned int)__builtin_bit_cast(unsigned short, (f16)hn);
            }
            #pragma unroll
            for (int reg = 0; reg < 4; ++reg) {
                unsigned int ob = (unsigned int)__shfl_xor((int)hb[reg], 1, 64);
                if ((lane & 1) == 0) {
                    size_t eidx = (size_t)(rowbase + quad * 4 + reg) * HH + jbase + myrow;
                    __hip_atomic_store(dstw + (eidx >> 1), hb[reg] | (ob << 16),
                                       __ATOMIC_RELAXED, __HIP_MEMORY_SCOPE_AGENT);
                }
            }
            // per-wave release: drain sc1 stores to coherence point, then flag
            __builtin_amdgcn_s_waitcnt(0);
            if (lane == 0)
                __hip_atomic_store(fmine, (unsigned)(t + 1),
                                   __ATOMIC_RELAXED, __HIP_MEMORY_SCOPE_AGENT);
        }

        // ---- readout partial: y_{t-1} += h_t[:, c*64:c*64+64] . W_out^T ----
        if (t >= 1) {
            f32x4 ya = {0.f,0.f,0.f,0.f};
            f16x8 a0 = *(const f16x8*)&hg[l16][c * 64 + quad * 8];
            f16x8 a1 = *(const f16x8*)&hg[l16][c * 64 + 32 + quad * 8];
            ya = __builtin_amdgcn_mfma_f32_16x16x32_f16(a0, bfo[0], ya, 0, 0, 0);
            ya = __builtin_amdgcn_mfma_f32_16x16x32_f16(a1, bfo[1], ya, 0, 0, 0);
            #pragma unroll
            for (int reg = 0; reg < 4; ++reg)
                atomicAdd(yout + ((size_t)(rowbase + quad * 4 + reg) * TT + (t - 1)) * OO + myrow,
                          ya[reg] + biaso);
        }
        __syncthreads();   // B2: hg/xsh reads done before next iter's writes
    }
}

extern "C" void kernel_launch(void* const* d_in, const int* in_sizes, int n_in,
                              void* d_out, int out_size, void* d_ws, size_t ws_size,
                              hipStream_t stream)
{
    const float* x    = (const float*)d_in[0];
    const float* Wxh  = (const float*)d_in[1];
    const float* Whh  = (const float*)d_in[2];
    const float* bh   = (const float*)d_in[3];
    const float* Wout = (const float*)d_in[4];
    const float* bout = (const float*)d_in[5];
    float* yout = (float*)d_out;

    f16* hbuf = (f16*)d_ws;
    const size_t hbuf_bytes = (size_t)2 * BB * HH * sizeof(f16);      // 512 KB
    unsigned int* flg = (unsigned int*)((char*)d_ws + hbuf_bytes);
    const size_t flg_bytes = (size_t)NG * NC * 4 * sizeof(unsigned int); // 2 KB

    if (ws_size < hbuf_bytes + flg_bytes) return;

    hipMemsetAsync(flg, 0, flg_bytes, stream);
    hipMemsetAsync(yout, 0, (size_t)out_size * sizeof(float), stream); // atomic targets

    // 128 blocks (<=256 CUs, ~21KB LDS, ~160 VGPR) -> all co-resident.
    eirnn_persist<<<dim3(NG * NC), dim3(256), 0, stream>>>(
        x, Wxh, Whh, bh, Wout, bout, yout, hbuf, flg);
}